// Round 5
// baseline (446.356 us; speedup 1.0000x reference)
//
#include <hip/hip_runtime.h>
#include <hip/hip_bf16.h>

#define N_NODES 50000
#define N_EDGES 1600000
#define D 512

typedef __attribute__((ext_vector_type(8))) short short8;
typedef __attribute__((ext_vector_type(4))) float f32x4;
typedef __attribute__((ext_vector_type(2))) float f32x2;
typedef __attribute__((ext_vector_type(8))) unsigned short u16x8;

__device__ __forceinline__ void async_copy16(const void* g, void* l) {
    __builtin_amdgcn_global_load_lds(
        (const __attribute__((address_space(1))) unsigned int*)g,
        (__attribute__((address_space(3))) unsigned int*)l, 16, 0, 0);
}

// --- W transpose + cast: Wt[n][k] = bf16(W[k][n]) ---
__global__ __launch_bounds__(256) void wt_kernel(const float* __restrict__ W,
                                                 unsigned short* __restrict__ Wt) {
    int idx = blockIdx.x * 256 + threadIdx.x;
    int k = idx >> 9;
    int n = idx & 511;
    Wt[n * D + k] = __bfloat16_as_ushort(__float2bfloat16(W[k * D + n]));
}

// --- CSR row_start from sorted adj_rows ---
__global__ __launch_bounds__(256) void rowptr_kernel(const int* __restrict__ rows,
                                                     int* __restrict__ row_start) {
    int r = blockIdx.x * 256 + threadIdx.x;
    if (r > N_NODES) return;
    int lo = 0, hi = N_EDGES;
    while (lo < hi) {
        int mid = (lo + hi) >> 1;
        if (rows[mid] < r) lo = mid + 1; else hi = mid;
    }
    row_start[r] = lo;
}

// --- support = bf16(bf16(X) @ Wt^T), fused fp32->bf16 in A staging ---
// v5 = v4 with __launch_bounds__(512, 2). v4's (512,4) capped VGPR at 128 while
// the kernel needs ~130-150 (acc 64 + frags 32 + staging 12 + addr ~20) ->
// guaranteed K-loop scratch spills = VMEM on the critical path every iter
// (gemm ran ~210us vs 42us traffic floor). (512,2) caps at 256 VGPR: no spills,
// 8 waves (2/SIMD) resident, double-buffer + T14 staging order unchanged.
#define BM 128
#define BN 256
#define BK 32

__global__ __launch_bounds__(512, 2) void gemm_kernel(const float* __restrict__ X,
                                                      const unsigned short* __restrict__ Wt,
                                                      __hip_bfloat16* __restrict__ support) {
    __shared__ unsigned short As[2][BM * BK];   // 16 KB total
    __shared__ unsigned short Bs[2][BN * BK];   // 32 KB total

    const int t = threadIdx.x;
    const int lane = t & 63;
    const int w = t >> 6;
    const int wm = (w >> 2) * 64;          // 2 M-waves
    const int wn = (w & 3) * 64;           // 4 N-waves
    const int bid = blockIdx.x;
    const int m0 = (bid >> 1) * BM;        // n-fast: siblings share A panel in L2
    const int n0 = (bid & 1) * BN;
    const int l15 = lane & 15;
    const int quad = lane >> 4;

    f32x4 acc[4][4];
#pragma unroll
    for (int i = 0; i < 4; ++i)
#pragma unroll
        for (int j = 0; j < 4; ++j) acc[i][j] = (f32x4)(0.0f);

    // A staging: thread t loads 8 f32 of row (t>>2), cols (t&3)*8 .. +8
    int arow = m0 + (t >> 2);
    if (arow > N_NODES - 1) arow = N_NODES - 1;
    const float* abase = X + (size_t)arow * D + (t & 3) * 8;
    const int awr = (t >> 2) * BK + (t & 3) * 8;   // LDS offset (shorts), 16B-aligned

    // B staging: chunk cid = c*512 + t; n = cid>>2, kc = cid&3
    // dest = Bs + cid*8 shorts (lane-linear within each wave-instr), src per-lane.

    // ---- prologue: stage K-tile 0 into buffer 0 ----
    {
        f32x4 a0 = *(const f32x4*)abase;
        f32x4 a1 = *(const f32x4*)(abase + 4);
#pragma unroll
        for (int c = 0; c < 2; ++c) {
            int cid = c * 512 + t;
            async_copy16(Wt + (size_t)(n0 + (cid >> 2)) * D + (cid & 3) * 8,
                         &Bs[0][cid * 8]);
        }
        u16x8 u;
#pragma unroll
        for (int k = 0; k < 4; ++k) {
            u[k]     = __bfloat16_as_ushort(__float2bfloat16(a0[k]));
            u[k + 4] = __bfloat16_as_ushort(__float2bfloat16(a1[k]));
        }
        *(u16x8*)(&As[0][awr]) = u;
    }
    __syncthreads();

    int cur = 0;
    for (int kt = 0; kt < D / BK; ++kt) {
        f32x4 a0n, a1n;
        const int nxt = cur ^ 1;
        if (kt < D / BK - 1) {
            const int k0n = (kt + 1) * BK;
            // A loads first (so their waitcnt leaves B asyncs in flight)
            a0n = *(const f32x4*)(abase + k0n);
            a1n = *(const f32x4*)(abase + k0n + 4);
#pragma unroll
            for (int c = 0; c < 2; ++c) {
                int cid = c * 512 + t;
                async_copy16(Wt + (size_t)(n0 + (cid >> 2)) * D + k0n + (cid & 3) * 8,
                             &Bs[nxt][cid * 8]);
            }
        }

        short8 af[4], bf[4];
#pragma unroll
        for (int i = 0; i < 4; ++i) af[i] = *(const short8*)(&As[cur][(wm + i * 16 + l15) * BK + quad * 8]);
#pragma unroll
        for (int j = 0; j < 4; ++j) bf[j] = *(const short8*)(&Bs[cur][(wn + j * 16 + l15) * BK + quad * 8]);
#pragma unroll
        for (int i = 0; i < 4; ++i)
#pragma unroll
            for (int j = 0; j < 4; ++j)
                acc[i][j] = __builtin_amdgcn_mfma_f32_16x16x32_bf16(af[i], bf[j], acc[i][j], 0, 0, 0);

        if (kt < D / BK - 1) {
            u16x8 u;
#pragma unroll
            for (int k = 0; k < 4; ++k) {
                u[k]     = __bfloat16_as_ushort(__float2bfloat16(a0n[k]));
                u[k + 4] = __bfloat16_as_ushort(__float2bfloat16(a1n[k]));
            }
            *(u16x8*)(&As[nxt][awr]) = u;
        }
        __syncthreads();
        cur ^= 1;
    }

#pragma unroll
    for (int i = 0; i < 4; ++i) {
        int grow = m0 + wm + i * 16 + quad * 4;
#pragma unroll
        for (int j = 0; j < 4; ++j) {
            int gc = n0 + wn + j * 16 + l15;
#pragma unroll
            for (int rr = 0; rr < 4; ++rr) {
                int gr = grow + rr;
                if (gr < N_NODES)
                    support[(size_t)gr * D + gc] = __float2bfloat16(acc[i][j][rr]);
            }
        }
    }
}

// --- SpMM: block per row (r0 proven layout), 8-edge unroll, nt-stores — UNCHANGED (control) ---
__global__ __launch_bounds__(256) void spmm_kernel(const unsigned short* __restrict__ support,
                                                   const int* __restrict__ cols,
                                                   const float* __restrict__ vals,
                                                   const int* __restrict__ row_start,
                                                   float* __restrict__ out) {
    const int r = blockIdx.x;
    const int t = threadIdx.x;           // thread owns cols 2t, 2t+1
    const int s = row_start[r];
    const int e = row_start[r + 1];
    const size_t co = 2 * t;

    float ax = 0.f, ay = 0.f;
    int i = s;
    for (; i + 8 <= e; i += 8) {
        int c[8]; float v[8]; unsigned int h[8];
#pragma unroll
        for (int k = 0; k < 8; ++k) { c[k] = cols[i + k]; v[k] = vals[i + k]; }
#pragma unroll
        for (int k = 0; k < 8; ++k)
            h[k] = *(const unsigned int*)(support + (size_t)c[k] * D + co);
#pragma unroll
        for (int k = 0; k < 8; ++k) {
            ax += v[k] * __uint_as_float(h[k] << 16);          // lo bf16
            ay += v[k] * __uint_as_float(h[k] & 0xffff0000u);  // hi bf16
        }
    }
    for (; i < e; ++i) {
        int c = cols[i];
        float v = vals[i];
        unsigned int h = *(const unsigned int*)(support + (size_t)c * D + co);
        ax += v * __uint_as_float(h << 16);
        ay += v * __uint_as_float(h & 0xffff0000u);
    }
    f32x2 o; o[0] = ax; o[1] = ay;
    // nontemporal: out is streamed once; keep it out of L2 so gathers keep their lines
    __builtin_nontemporal_store(o, (f32x2*)(out + (size_t)r * D + co));
}

extern "C" void kernel_launch(void* const* d_in, const int* in_sizes, int n_in,
                              void* d_out, int out_size, void* d_ws, size_t ws_size,
                              hipStream_t stream) {
    (void)in_sizes; (void)n_in; (void)out_size; (void)ws_size;
    const float* X    = (const float*)d_in[0];
    const float* W    = (const float*)d_in[1];
    const int* rows   = (const int*)d_in[2];
    const int* cols   = (const int*)d_in[3];
    const float* vals = (const float*)d_in[4];
    float* out = (float*)d_out;

    unsigned short* support = (unsigned short*)d_ws;            // 51.2 MB
    unsigned short* Wt      = support + (size_t)N_NODES * D;    // 0.5 MB
    int* row_start          = (int*)(Wt + (size_t)D * D);       // 200 KB

    wt_kernel<<<(D * D) / 256, 256, 0, stream>>>(W, Wt);
    rowptr_kernel<<<(N_NODES + 256) / 256, 256, 0, stream>>>(rows, row_start);

    const int mblocks = (N_NODES + BM - 1) / BM;   // 391
    gemm_kernel<<<mblocks * 2, 512, 0, stream>>>(X, Wt, (__hip_bfloat16*)support);

    spmm_kernel<<<N_NODES, 256, 0, stream>>>(support, cols, vals, row_start, out);
}